// Round 4
// baseline (315.628 us; speedup 1.0000x reference)
//
#include <hip/hip_runtime.h>

// Circle (ball) projection: out = center + (x-center) * min(1, R/max(||x-center||,1e-12))
// B = 8,388,608 points, 3 fp32 coords, AoS [B,3].
//
// R3 = R2 with the compile fix: __builtin_nontemporal_store requires a native
// clang vector type, not HIP's float4 wrapper class. Use fvec4 =
// ext_vector_type(4) float throughout.
//
// Experiment (unchanged from R2): discriminate latency/MLP-bound vs
// platform-BW-bound. 8 points/thread = 12 independent float4 loads in flight
// per lane, no LDS, no barriers, nontemporal stores.
// npts = 8,388,608 -> 1,048,576 threads -> 4096 blocks x 256.

#define RADIUS 1.0f

typedef float fvec4 __attribute__((ext_vector_type(4)));

__global__ __launch_bounds__(256) void circle_proj_ilp(
    const fvec4* __restrict__ xv,
    const fvec4* __restrict__ cv,
    fvec4* __restrict__ ov,
    int ngroups)  // number of 8-point groups
{
    int t = blockIdx.x * blockDim.x + threadIdx.x;
    if (t >= ngroups) return;
    long base = (long)t * 6;

    // Issue all 12 loads up front (independent -> 12 vmem in flight per lane)
    fvec4 xr[6], cr[6];
#pragma unroll
    for (int k = 0; k < 6; ++k) xr[k] = xv[base + k];
#pragma unroll
    for (int k = 0; k < 6; ++k) cr[k] = cv[base + k];

    float px[24], pc[24], po[24];
#pragma unroll
    for (int k = 0; k < 6; ++k) {
#pragma unroll
        for (int j = 0; j < 4; ++j) {
            px[4*k + j] = xr[k][j];
            pc[4*k + j] = cr[k][j];
        }
    }

#pragma unroll
    for (int p = 0; p < 8; ++p) {
        float dx = px[3*p + 0] - pc[3*p + 0];
        float dy = px[3*p + 1] - pc[3*p + 1];
        float dz = px[3*p + 2] - pc[3*p + 2];
        float n  = sqrtf(dx*dx + dy*dy + dz*dz);
        float scale = fminf(1.0f, RADIUS / fmaxf(n, 1e-12f));
        po[3*p + 0] = pc[3*p + 0] + dx * scale;
        po[3*p + 1] = pc[3*p + 1] + dy * scale;
        po[3*p + 2] = pc[3*p + 2] + dz * scale;
    }

#pragma unroll
    for (int k = 0; k < 6; ++k) {
        fvec4 o = {po[4*k+0], po[4*k+1], po[4*k+2], po[4*k+3]};
        __builtin_nontemporal_store(o, &ov[base + k]);
    }
}

extern "C" void kernel_launch(void* const* d_in, const int* in_sizes, int n_in,
                              void* d_out, int out_size, void* d_ws, size_t ws_size,
                              hipStream_t stream) {
    const float* x = (const float*)d_in[0];   // [B,3] fp32
    const float* c = (const float*)d_in[1];   // [B,3] fp32
    float* out = (float*)d_out;

    long total_floats = in_sizes[0];          // B*3 = 25,165,824
    int ngroups = (int)(total_floats / 24);   // 8 points per thread = 1,048,576

    int block = 256;
    int grid = (ngroups + block - 1) / block; // 4096

    circle_proj_ilp<<<grid, block, 0, stream>>>(
        (const fvec4*)x, (const fvec4*)c, (fvec4*)out, ngroups);
}

// Round 5
// 242.865 us; speedup vs baseline: 1.2996x; 1.2996x over previous
//
#include <hip/hip_runtime.h>

// Circle (ball) projection: out = center + (x-center) * min(1, R/max(||x-center||,1e-12))
// B = 8,388,608 points, 3 fp32 coords, AoS [B,3].
//
// R4 = R3 minus nontemporal stores. R3's nt stores bypassed L2 write-merging
// -> WRITE_SIZE doubled (96 -> 195 MiB) and dur regressed 91 -> 167 us.
// Regular stores restore L2 merge. This leaves a clean MLP experiment:
//   - 8 points/thread = 12 independent 16B loads in flight per lane
//     (2x the in-flight bytes of R0/R1)
//   - no LDS, no barriers (no phase gating)
// npts = 8,388,608 -> 1,048,576 threads -> 4096 blocks x 256 (exact).

#define RADIUS 1.0f

typedef float fvec4 __attribute__((ext_vector_type(4)));

__global__ __launch_bounds__(256) void circle_proj_ilp8(
    const fvec4* __restrict__ xv,
    const fvec4* __restrict__ cv,
    fvec4* __restrict__ ov,
    int ngroups)  // number of 8-point groups
{
    int t = blockIdx.x * blockDim.x + threadIdx.x;
    if (t >= ngroups) return;
    long base = (long)t * 6;

    // Issue all 12 loads up front (independent -> 12 vmem in flight per lane)
    fvec4 xr[6], cr[6];
#pragma unroll
    for (int k = 0; k < 6; ++k) xr[k] = xv[base + k];
#pragma unroll
    for (int k = 0; k < 6; ++k) cr[k] = cv[base + k];

    float px[24], pc[24], po[24];
#pragma unroll
    for (int k = 0; k < 6; ++k) {
#pragma unroll
        for (int j = 0; j < 4; ++j) {
            px[4*k + j] = xr[k][j];
            pc[4*k + j] = cr[k][j];
        }
    }

#pragma unroll
    for (int p = 0; p < 8; ++p) {
        float dx = px[3*p + 0] - pc[3*p + 0];
        float dy = px[3*p + 1] - pc[3*p + 1];
        float dz = px[3*p + 2] - pc[3*p + 2];
        float n  = sqrtf(dx*dx + dy*dy + dz*dz);
        float scale = fminf(1.0f, RADIUS / fmaxf(n, 1e-12f));
        po[3*p + 0] = pc[3*p + 0] + dx * scale;
        po[3*p + 1] = pc[3*p + 1] + dy * scale;
        po[3*p + 2] = pc[3*p + 2] + dz * scale;
    }

#pragma unroll
    for (int k = 0; k < 6; ++k) {
        fvec4 o = {po[4*k+0], po[4*k+1], po[4*k+2], po[4*k+3]};
        ov[base + k] = o;
    }
}

extern "C" void kernel_launch(void* const* d_in, const int* in_sizes, int n_in,
                              void* d_out, int out_size, void* d_ws, size_t ws_size,
                              hipStream_t stream) {
    const float* x = (const float*)d_in[0];   // [B,3] fp32
    const float* c = (const float*)d_in[1];   // [B,3] fp32
    float* out = (float*)d_out;

    long total_floats = in_sizes[0];          // B*3 = 25,165,824
    int ngroups = (int)(total_floats / 24);   // 8 points per thread = 1,048,576

    int block = 256;
    int grid = (ngroups + block - 1) / block; // 4096

    circle_proj_ilp8<<<grid, block, 0, stream>>>(
        (const fvec4*)x, (const fvec4*)c, (fvec4*)out, ngroups);
}